// Round 7
// baseline (26.202 us; speedup 1.0000x reference)
//
#include <hip/hip_runtime.h>
#include <math.h>

// Problem shape (fixed by setup_inputs)
#define Bb 2
#define Vv 3
#define Nn 4096
#define NDIR 16
#define NRB 32           // rowblocks per dir
#define RPB 128          // max rows per block
#define NBLKS (NDIR*NRB) // 512
#define PADW 1.5e38f

// ws (uint view): [0..511] partial bits, [512..1023] ~partial bits

__device__ __forceinline__ unsigned dummy(){ return 0; }

// packed u = a*x + w ; u = a2*y + u ; u = a3*z + u   (all 2-wide f32)
__device__ __forceinline__ float2 pk3fma(float2 ax2, float2 ay2, float2 az2,
                                         float2 xp, float2 yp, float2 zp, float2 wp){
    float2 u;
    asm("v_pk_fma_f32 %0, %1, %4, %7\n\t"
        "v_pk_fma_f32 %0, %2, %5, %0\n\t"
        "v_pk_fma_f32 %0, %3, %6, %0"
        : "=&v"(u)
        : "v"(ax2), "v"(ay2), "v"(az2), "v"(xp), "v"(yp), "v"(zp), "v"(wp));
    return u;
}

__device__ __forceinline__ void slots_for_dir(int dir, int* sA, int* sB){
    int k = dir & 3, bi = dir >> 2, b = bi >> 1;
    switch (k){
        case 0:  *sA = b;       *sB = 6 + bi;  break;  // fwd d_ab: rows ref, cols p2r
        case 1:  *sA = 6 + bi;  *sB = b;       break;  // fwd d_ba
        case 2:  *sA = 2 + bi;  *sB = 10 + bi; break;  // bwd d_ab: rows tgt, cols r2t
        default: *sA = 10 + bi; *sB = 2 + bi;  break;  // bwd d_ba
    }
}

// slot -> (b, view for depth/mask, M[9], tv[3]) ; point = M*(x,y,1)*d + tv
__device__ __forceinline__ void build_matrix(int slot,
                                             const float* __restrict__ poses,
                                             const float* __restrict__ intr,
                                             float* M, float* tv, int* bOut, int* vOut){
    int type, b, im1;
    if (slot < 2)      { type = 0; b = slot;         im1 = 0; }
    else if (slot < 6) { type = 1; b = (slot-2)>>1;  im1 = (slot-2)&1; }
    else if (slot < 10){ type = 2; b = (slot-6)>>1;  im1 = (slot-6)&1; }
    else               { type = 3; b = (slot-10)>>1; im1 = (slot-10)&1; }
    int vi = im1 + 1;
    *bOut = b;
    *vOut = (type==0 || type==3) ? 0 : vi;

    const float* Km = intr + b*9;
    float ka=Km[0],kb=Km[1],kc=Km[2],kd=Km[3],ke=Km[4],kf=Km[5],kg=Km[6],kh=Km[7],ki=Km[8];
    float c00=(ke*ki-kf*kh), c10=-(kd*ki-kf*kg), c20=(kd*kh-ke*kg);
    float det = ka*c00 + kb*c10 + kc*c20, iv = 1.0f/det;
    float Ki[9] = { c00*iv, -(kb*ki-kc*kh)*iv,  (kb*kf-kc*ke)*iv,
                    c10*iv,  (ka*ki-kc*kg)*iv, -(ka*kf-kc*kd)*iv,
                    c20*iv, -(ka*kh-kb*kg)*iv,  (ka*ke-kb*kd)*iv };
    tv[0] = tv[1] = tv[2] = 0.f;
    if (type < 2){
        #pragma unroll
        for (int i = 0; i < 9; ++i) M[i] = Ki[i];
        return;
    }
    const float* P0 = poses + (b*Vv + 0)*16;
    const float* Pi = poses + (b*Vv + vi)*16;
    float R[9];
    if (type == 2){  // inv(pose0) @ pose_i
        #pragma unroll
        for (int r = 0; r < 3; ++r){
            #pragma unroll
            for (int c = 0; c < 3; ++c)
                R[r*3+c] = P0[0*4+r]*Pi[0*4+c] + P0[1*4+r]*Pi[1*4+c] + P0[2*4+r]*Pi[2*4+c];
            tv[r] = P0[0*4+r]*(Pi[3]-P0[3]) + P0[1*4+r]*(Pi[7]-P0[7]) + P0[2*4+r]*(Pi[11]-P0[11]);
        }
    } else {         // inv(pose_i) @ pose0
        #pragma unroll
        for (int r = 0; r < 3; ++r){
            #pragma unroll
            for (int c = 0; c < 3; ++c)
                R[r*3+c] = Pi[0*4+r]*P0[0*4+c] + Pi[1*4+r]*P0[1*4+c] + Pi[2*4+r]*P0[2*4+c];
            tv[r] = Pi[0*4+r]*(P0[3]-Pi[3]) + Pi[1*4+r]*(P0[7]-Pi[7]) + Pi[2*4+r]*(P0[11]-Pi[11]);
        }
    }
    #pragma unroll
    for (int r = 0; r < 3; ++r)
        #pragma unroll
        for (int c = 0; c < 3; ++c)
            M[r*3+c] = R[r*3+0]*Ki[0*3+c] + R[r*3+1]*Ki[1*3+c] + R[r*3+2]*Ki[2*3+c];
}

// Single fused kernel (de-aliased bid mapping, packed-f32 inner loop).
__global__ void __launch_bounds__(256) fused_kernel(const float* __restrict__ poses,
                                                    const float* __restrict__ masks,
                                                    const float* __restrict__ intr,
                                                    const float* __restrict__ depth,
                                                    float* __restrict__ ws,
                                                    float* __restrict__ out){
    __shared__ __align__(16) float sbx[Nn + 16];
    __shared__ __align__(16) float sby[Nn + 16];
    __shared__ __align__(16) float sbz[Nn + 16];
    __shared__ __align__(16) float sbw[Nn + 16];   // NEGATED 0.5*|p|^2
    __shared__ float4 sA[RPB];
    __shared__ int   wsum[4];
    __shared__ float sred[32];

    int bid = blockIdx.x;
    int dir    = bid & (NDIR-1);   // low bits: de-alias active blocks across CUs
    int rowblk = bid >> 4;
    int slotA, slotB;
    slots_for_dir(dir, &slotA, &slotB);

    int tid = threadIdx.x;
    int lane = tid & 63, wv = tid >> 6;

    float MA[9], tA[3], MB[9], tB[3];
    int b, vA, vB, bdummy;
    build_matrix(slotA, poses, intr, MA, tA, &b, &vA);
    build_matrix(slotB, poses, intr, MB, tB, &bdummy, &vB);

    // ---- A phase: mask scan for cntA and this block's row slice ----
    unsigned flA = 0; int tsA = 0;
    float dvA[16];
    {
        const float* mb = masks + (b*Vv + vA)*Nn + tid*16;
        const float* db = depth + (b*Vv + vA)*Nn + tid*16;
        #pragma unroll
        for (int q = 0; q < 4; ++q){
            float4 m4 = *(const float4*)(mb + q*4);
            float4 d4 = *(const float4*)(db + q*4);
            const float* mv = (const float*)&m4;
            const float* dd = (const float*)&d4;
            #pragma unroll
            for (int r = 0; r < 4; ++r){
                dvA[q*4+r] = dd[r];
                if (mv[r] > 0.5f){ flA |= 1u << (q*4 + r); ++tsA; }
            }
        }
    }
    int inc = tsA;
    #pragma unroll
    for (int off = 1; off < 64; off <<= 1){
        int t = __shfl_up(inc, off, 64);
        if (lane >= off) inc += t;
    }
    if (lane == 63) wsum[wv] = inc;
    __syncthreads();
    int base = inc - tsA;
    #pragma unroll
    for (int w = 0; w < 4; ++w) if (w < wv) base += wsum[w];
    int cntA = wsum[0] + wsum[1] + wsum[2] + wsum[3];

    int lo = rowblk * RPB;
    int nRows = min(cntA - lo, RPB);
    float partial = 0.f;

    if (nRows > 0){
        // write A slice points
        {
            int p = base;
            #pragma unroll
            for (int k = 0; k < 16; ++k){
                if (flA & (1u << k)){
                    int rel = p - lo;
                    if (rel >= 0 && rel < RPB){
                        int n = tid*16 + k;
                        float d = dvA[k];
                        float x = (float)(n & 63), y = (float)(n >> 6);
                        float ux = fmaf(MA[0],x, fmaf(MA[1],y, MA[2]));
                        float uy = fmaf(MA[3],x, fmaf(MA[4],y, MA[5]));
                        float uz = fmaf(MA[6],x, fmaf(MA[7],y, MA[8]));
                        float px = fmaf(ux,d,tA[0]), py = fmaf(uy,d,tA[1]), pz = fmaf(uz,d,tA[2]);
                        sA[rel] = make_float4(px,py,pz, 0.5f*(px*px+py*py+pz*pz));
                    }
                    ++p;
                }
            }
        }
        __syncthreads();   // A writes done; wsum free for reuse

        // ---- B phase: full compacted cloud into LDS (SoA, negated w) ----
        unsigned flB = 0; int tsB = 0;
        float dv[16];
        {
            const float* mb = masks + (b*Vv + vB)*Nn + tid*16;
            const float* db = depth + (b*Vv + vB)*Nn + tid*16;
            #pragma unroll
            for (int q = 0; q < 4; ++q){
                float4 m4 = *(const float4*)(mb + q*4);
                float4 d4 = *(const float4*)(db + q*4);
                const float* mv = (const float*)&m4;
                const float* dd = (const float*)&d4;
                #pragma unroll
                for (int r = 0; r < 4; ++r){
                    dv[q*4+r] = dd[r];
                    if (mv[r] > 0.5f){ flB |= 1u << (q*4 + r); ++tsB; }
                }
            }
        }
        int incB = tsB;
        #pragma unroll
        for (int off = 1; off < 64; off <<= 1){
            int t = __shfl_up(incB, off, 64);
            if (lane >= off) incB += t;
        }
        if (lane == 63) wsum[wv] = incB;
        __syncthreads();
        int baseB = incB - tsB;
        #pragma unroll
        for (int w = 0; w < 4; ++w) if (w < wv) baseB += wsum[w];
        int cntB = wsum[0] + wsum[1] + wsum[2] + wsum[3];

        {
            int p = baseB;
            #pragma unroll
            for (int k = 0; k < 16; ++k){
                if (flB & (1u << k)){
                    int n = tid*16 + k;
                    float d = dv[k];
                    float x = (float)(n & 63), y = (float)(n >> 6);
                    float ux = fmaf(MB[0],x, fmaf(MB[1],y, MB[2]));
                    float uy = fmaf(MB[3],x, fmaf(MB[4],y, MB[5]));
                    float uz = fmaf(MB[6],x, fmaf(MB[7],y, MB[8]));
                    float px = fmaf(ux,d,tB[0]), py = fmaf(uy,d,tB[1]), pz = fmaf(uz,d,tB[2]);
                    sbx[p] = px; sby[p] = py; sbz[p] = pz;
                    sbw[p] = -0.5f*(px*px + py*py + pz*pz);
                    ++p;
                }
            }
        }
        int cntBp = (cntB + 15) & ~15;
        if (tid < cntBp - cntB){
            sbx[cntB+tid] = 0.f; sby[cntB+tid] = 0.f; sbz[cntB+tid] = 0.f;
            sbw[cntB+tid] = -PADW;
        }
        __syncthreads();

        // ---- pair loop: 32 rowgrps (4 rows) x 8 colparts, packed f32 ----
        int rowgrp = tid >> 3, colpart = tid & 7;
        int rbase = rowgrp * 4;
        float4 a0 = sA[rbase+0], a1 = sA[rbase+1], a2 = sA[rbase+2], a3 = sA[rbase+3];
        float2 a0x = {a0.x,a0.x}, a0y = {a0.y,a0.y}, a0z = {a0.z,a0.z};
        float2 a1x = {a1.x,a1.x}, a1y = {a1.y,a1.y}, a1z = {a1.z,a1.z};
        float2 a2x = {a2.x,a2.x}, a2y = {a2.y,a2.y}, a2z = {a2.z,a2.z};
        float2 a3x = {a3.x,a3.x}, a3y = {a3.y,a3.y}, a3z = {a3.z,a3.z};
        float m0 = -3.0e38f, m1 = -3.0e38f, m2 = -3.0e38f, m3 = -3.0e38f;

        int nIter = cntBp >> 4;        // 16 columns (8 pairs) per iter
        int o = 2*colpart;
        for (int j = 0; j < nIter; ++j){
            float2 xp = *(const float2*)&sbx[o];
            float2 yp = *(const float2*)&sby[o];
            float2 zp = *(const float2*)&sbz[o];
            float2 wp = *(const float2*)&sbw[o];
            float2 u;
            u = pk3fma(a0x,a0y,a0z, xp,yp,zp, wp); m0 = fmaxf(fmaxf(u.x,u.y), m0);
            u = pk3fma(a1x,a1y,a1z, xp,yp,zp, wp); m1 = fmaxf(fmaxf(u.x,u.y), m1);
            u = pk3fma(a2x,a2y,a2z, xp,yp,zp, wp); m2 = fmaxf(fmaxf(u.x,u.y), m2);
            u = pk3fma(a3x,a3y,a3z, xp,yp,zp, wp); m3 = fmaxf(fmaxf(u.x,u.y), m3);
            o += 16;
        }
        // exact per-row max over 8 colparts
        #pragma unroll
        for (int off = 1; off < 8; off <<= 1){
            m0 = fmaxf(m0, __shfl_xor(m0, off, 64));
            m1 = fmaxf(m1, __shfl_xor(m1, off, 64));
            m2 = fmaxf(m2, __shfl_xor(m2, off, 64));
            m3 = fmaxf(m3, __shfl_xor(m3, off, 64));
        }
        if (colpart == 0){
            float s = 0.f;
            if (rbase + 0 < nRows) s += 2.0f*(a0.w - m0);
            if (rbase + 1 < nRows) s += 2.0f*(a1.w - m1);
            if (rbase + 2 < nRows) s += 2.0f*(a2.w - m2);
            if (rbase + 3 < nRows) s += 2.0f*(a3.w - m3);
            sred[rowgrp] = s;
        }
        __syncthreads();
        if (tid == 0){
            float tsum = 0.f;
            #pragma unroll
            for (int g = 0; g < 16; ++g) tsum += sred[g] + sred[g+16];
            partial = tsum / (fmaxf((float)cntA, 1.0f) * 16.0f);
        }
    }

    // ---- publish self-validating pair (bits, ~bits) ----
    unsigned* wsu = (unsigned*)ws;
    if (tid == 0){
        unsigned pb = __float_as_uint(partial);
        atomicExch(&wsu[bid], pb);
        atomicExch(&wsu[NBLKS + bid], ~pb);
    }
    if (bid != 0) return;

    // ---- block 0: wait for all 512 consistent pairs, fixed-order sum ----
    __syncthreads();
    float p0, p1;
    {
        unsigned va, vb;
        for (;;){
            va = atomicAdd(&wsu[tid], 0u);
            vb = atomicAdd(&wsu[NBLKS + tid], 0u);
            if (va == ~vb) break;
            __builtin_amdgcn_s_sleep(1);
        }
        p0 = __uint_as_float(va);
        for (;;){
            va = atomicAdd(&wsu[tid + 256], 0u);
            vb = atomicAdd(&wsu[NBLKS + tid + 256], 0u);
            if (va == ~vb) break;
            __builtin_amdgcn_s_sleep(1);
        }
        p1 = __uint_as_float(va);
    }
    float v = p0 + p1;
    for (int off = 32; off > 0; off >>= 1) v += __shfl_down(v, off, 64);
    if (lane == 0) sred[wv] = v;
    __syncthreads();
    if (tid == 0) out[0] = sred[0] + sred[1] + sred[2] + sred[3];
}

extern "C" void kernel_launch(void* const* d_in, const int* in_sizes, int n_in,
                              void* d_out, int out_size, void* d_ws, size_t ws_size,
                              hipStream_t stream) {
    // inputs: 0 views (unused), 1 poses, 2 masks, 3 intrinsics, 4 depth_maps, 5 num_views
    const float* poses = (const float*)d_in[1];
    const float* masks = (const float*)d_in[2];
    const float* intr  = (const float*)d_in[3];
    const float* depth = (const float*)d_in[4];
    float* ws  = (float*)d_ws;
    float* out = (float*)d_out;

    fused_kernel<<<NBLKS, 256, 0, stream>>>(poses, masks, intr, depth, ws, out);
}